// Round 6
// baseline (150.988 us; speedup 1.0000x reference)
//
#include <hip/hip_runtime.h>

#define N_NODES  50000
#define N_EDGES  600000
#define CHANNELS 128
#define HEADS    8
#define HEAD_DIM 16     // CHANNELS / HEADS
#define CAP      64     // per-node capacity; degrees ~ Poisson(12), max ~28

#define NBINS    2048   // dst bins; bin = dst*NBINS/N_NODES (~25 nodes/bin)
#define CHUNK_E  4096   // edges per chunk
#define NCHUNK   ((N_EDGES + CHUNK_E - 1) / CHUNK_E)     // 147
#define CAPC     16     // per-(chunk,bin) fixed slice = one 64B line; Poisson(2), P(>16)~5e-11
#define NPB      28     // max nodes per bin (25) padded

#define LOGIT_VB ((N_NODES * (CHANNELS / 8)) / 256)      // 3125 (8 channels/thread)
#define NW       4      // waves per aggregate block

typedef float  f32x4 __attribute__((ext_vector_type(4)));   // nontemporal-store-able

// bf16 round-to-nearest-even of an fp32 bit pattern
__device__ __forceinline__ unsigned bf16rne(float f) {
    unsigned u = __float_as_uint(f);
    return (u + 0x7FFFu + ((u >> 16) & 1u)) >> 16;
}

// ---------------------------------------------------------------------------
// K1: logit sweep ∥ fixed-slice binscatter (disjoint block ranges, no
// ordering dependency, nothing pre-zeroed).
//  - blocks [0, NCHUNK): bin the chunk's 4096 edges.  Rank via LDS atomic
//    into the (chunk,bin) cell's FIXED 64B slice ebuf[bin][chunk][CAPC].
//    No hist/scan/global-atomic allocation (R3 lesson: same-address global
//    atomic chains serialize ~40-100ns each on the home L2; R1 lesson:
//    never scatter sub-line stores across a large region — here stores
//    cluster ~2 per 64B cell).
//  - blocks [NCHUNK, NCHUNK+LOGIT_VB): per-node logit halves + bf16(x)
//    (8 channels/thread: 32B in, 16B packed-bf16 out).
// ---------------------------------------------------------------------------
__global__ void prep_kernel(const float* __restrict__ x,
                            const float* __restrict__ att,
                            const int*   __restrict__ src,
                            const int*   __restrict__ dst,
                            float*          __restrict__ ls8,
                            float*          __restrict__ ld8,
                            unsigned short* __restrict__ xb,
                            unsigned*       __restrict__ ebuf,
                            int*            __restrict__ cc) {
    int b = blockIdx.x;
    int t = threadIdx.x;
    if (b < NCHUNK) {
        __shared__ int lh[NBINS];                // rank counters, 8 KB
#pragma unroll
        for (int k = 0; k < NBINS / 256; ++k) lh[t + k * 256] = 0;
        __syncthreads();
        int base = b * CHUNK_E;
#pragma unroll 4
        for (int k = 0; k < CHUNK_E / 256; ++k) {
            int e = base + t + k * 256;
            if (e < N_EDGES) {
                int d = dst[e];
                int s = src[e];
                unsigned bin = ((unsigned)d * NBINS) / N_NODES;
                int r = atomicAdd(&lh[bin], 1);              // LDS atomic
                if (r < CAPC)
                    ebuf[((size_t)bin * NCHUNK + b) * CAPC + r] =
                        (unsigned)s | ((unsigned)d << 16);
            }
        }
        __syncthreads();
#pragma unroll
        for (int k = 0; k < NBINS / 256; ++k) {
            int bin = t + k * 256;
            cc[(size_t)bin * NCHUNK + b] = min(lh[bin], CAPC);   // bin-major for K2
        }
        return;
    }
    int gid = (b - NCHUNK) * 256 + t;            // (node, 8-channel slot)
    int n  = gid >> 4;                           // 16 slots per node
    int c8 = gid & 15;
    int h  = c8 >> 1;                            // 2 slots per head
    int j8 = c8 & 1;

    const float4* xp = (const float4*)x + (size_t)gid * 2;
    float4 v0 = xp[0], v1 = xp[1];

    // packed bf16 store: 8 channels -> uint4 (16B)
    uint4 pk;
    pk.x = bf16rne(v0.x) | (bf16rne(v0.y) << 16);
    pk.y = bf16rne(v0.z) | (bf16rne(v0.w) << 16);
    pk.z = bf16rne(v1.x) | (bf16rne(v1.y) << 16);
    pk.w = bf16rne(v1.z) | (bf16rne(v1.w) << 16);
    ((uint4*)xb)[gid] = pk;

    // att row = 32 floats = 8 float4s: [a_src(4), a_dst(4)]
    const float4* att4 = (const float4*)att;
    float4 as0 = att4[h * 8 + j8 * 2],     as1 = att4[h * 8 + j8 * 2 + 1];
    float4 ad0 = att4[h * 8 + 4 + j8 * 2], ad1 = att4[h * 8 + 5 + j8 * 2];
    float ts = v0.x*as0.x + v0.y*as0.y + v0.z*as0.z + v0.w*as0.w
             + v1.x*as1.x + v1.y*as1.y + v1.z*as1.z + v1.w*as1.w;
    float td = v0.x*ad0.x + v0.y*ad0.y + v0.z*ad0.z + v0.w*ad0.w
             + v1.x*ad1.x + v1.y*ad1.y + v1.z*ad1.z + v1.w*ad1.w;
    ts += __shfl_xor(ts, 1, 2);
    td += __shfl_xor(td, 1, 2);
    if (j8 == 0) {
        ls8[n * HEADS + h] = ts;
        ld8[n * HEADS + h] = td;
    }
}

// ---------------------------------------------------------------------------
// K2: bucket + fused GAT merged.  One block per bin (~25 nodes).
// R4 counters: 51us, FETCH 85MB (xb gather misses dominate), Occupancy 33%,
// 27% HBM -> latency-bound.  R5: 2x blocks (8/CU), ~12KB LDS so all fit,
// nontemporal on streamed ebuf/out to keep L2 for the xb gather set.
// Phase 1: sparse read of the bin's fixed-slice segment (slot < cc[c]),
//   LDS-atomic rank into per-node LDS rows.
// Phase 2: per-wave node loop, proven fused body:
//   Pass 1 (h=lane>>3, j=lane&7): logits in registers, 8-lane shuffle max
//     (clamped at 0 == reference's max(seg_max,0)), one exp per (edge,head)
//     -> LDS s_p, denominator reduced in-register.
//   Pass 2: 4 edges per wave-load — uint4/lane (16B), 16 lanes = one 256B
//     bf16 row; 4-slot statically-indexed uint4 window.  q[] must only be
//     indexed by compile-time constants (R12: dynamic indexing spills,
//     3.6x regression).
// rows[] slots >= cnt are uninitialized LDS: every access is `< cnt`-guarded
// or shfl-index-clamped, so garbage is never dereferenced.
// ---------------------------------------------------------------------------
__global__ void aggregate_kernel(const unsigned* __restrict__ ebuf,
                                 const int*      __restrict__ cc,
                                 const unsigned short* __restrict__ xb,
                                 const float* __restrict__ ls8,
                                 const float* __restrict__ ld8,
                                 float*       __restrict__ out) {
    __shared__ unsigned short rows[NPB * CAP];   // 3.5 KB
    __shared__ int   lcnt[NPB];
    __shared__ int   lcc[NCHUNK];                // 588 B
    __shared__ float s_p[NW * CAP * HEADS];      // 8 KB: per-wave softmax stage

    int b = blockIdx.x;
    int t = threadIdx.x;
    int n0 = (b * N_NODES + NBINS - 1) / NBINS;
    int n1 = ((b + 1) * N_NODES + NBINS - 1) / NBINS;
    int nn = n1 - n0;
    if (t < NPB) lcnt[t] = 0;
    if (t < NCHUNK) lcc[t] = cc[(size_t)b * NCHUNK + t];
    __syncthreads();

    // ---- phase 1: rank bin's edges into per-node LDS rows ----
    const unsigned* seg = ebuf + (size_t)b * NCHUNK * CAPC;
    for (int p = t; p < NCHUNK * CAPC; p += 256) {
        int c    = p >> 4;                       // CAPC = 16
        int slot = p & 15;
        if (slot < lcc[c]) {
            unsigned rec = __builtin_nontemporal_load(&seg[p]);
            int s = (int)(rec & 0xFFFFu);
            int d = (int)(rec >> 16);
            int pos = atomicAdd(&lcnt[d - n0], 1);           // LDS atomic
            if (pos < CAP) rows[(d - n0) * CAP + pos] = (unsigned short)s;
        }
    }
    __syncthreads();

    // ---- phase 2: per-wave node loop, fused body ----
    int wave = t >> 6;
    int lane = t & 63;
    int h = lane >> 3;                           // pass-1 head
    int j = lane & 7;
    int r   = lane >> 4;                         // pass-2: which edge of quad (0..3)
    int l16 = lane & 15;                         // pass-2: channel octet
    int h2  = l16 >> 1;                          // pass-2 head
    float* sp = s_p + wave * (CAP * HEADS);

    for (int idx = wave; idx < nn; idx += NW) {
        int n = n0 + idx;
        int cnt_raw = lcnt[idx];
        int cnt = (cnt_raw > CAP) ? CAP : cnt_raw;
        int myidx = (int)rows[idx * CAP + lane];
        float ldst = ld8[n * HEADS + h];

        // ---- pass 1: logits in regs, per-head max, one exp per value ----
        float av[8];
        float mymax = -1e30f;
#pragma unroll
        for (int k = 0; k < 8; ++k) {
            int i = j + 8 * k;
            av[k] = -1e30f;
            if (i < cnt) {
                int   s  = __shfl(myidx, i);
                float lg = ls8[s * HEADS + h] + ldst;
                float a  = (lg >= 0.0f) ? lg : 0.2f * lg;   // LeakyReLU(0.2)
                av[k] = a;
                mymax = fmaxf(mymax, a);
            }
        }
#pragma unroll
        for (int o = 4; o >= 1; o >>= 1) mymax = fmaxf(mymax, __shfl_xor(mymax, o, 8));
        float m = fmaxf(mymax, 0.0f);            // reference clamps seg_max at 0

        float myl = 0.0f;
#pragma unroll
        for (int k = 0; k < 8; ++k) {
            int i = j + 8 * k;
            if (i < cnt) {
                float p = __expf(av[k] - m);
                sp[i * HEADS + h] = p;           // 2-way bank aliasing only
                myl += p;
            }
        }
#pragma unroll
        for (int o = 4; o >= 1; o >>= 1) myl += __shfl_xor(myl, o, 8);

        // ---- pass 2: weighted accumulate, 4 edges/load, 4 uint4 window ----
#define LO16(u) __uint_as_float((u) << 16)
#define HI16(u) __uint_as_float((u) & 0xFFFF0000u)
#define LP(kq) ( ((const uint4*)(xb + (size_t)__shfl(myidx, ((4*(kq)+r) < cnt) ? (4*(kq)+r) : 0) * CHANNELS))[l16] )
        uint4 q[4];
#pragma unroll
        for (int k = 0; k < 4; ++k) q[k] = LP(k);

        float a0 = 0.f, a1 = 0.f, a2 = 0.f, a3 = 0.f;
        float a4 = 0.f, a5 = 0.f, a6 = 0.f, a7 = 0.f;
        int nquad = (cnt + 3) >> 2;
        int k = 0;
        for (; k + 2 <= nquad; k += 2) {
#pragma unroll
            for (int u = 0; u < 2; ++u) {
                int e4 = 4 * (k + u) + r;
                float p = (e4 < cnt) ? sp[e4 * HEADS + h2] : 0.0f;
                uint4 qq = q[u];
                a0 += p * LO16(qq.x);
                a1 += p * HI16(qq.x);
                a2 += p * LO16(qq.y);
                a3 += p * HI16(qq.y);
                a4 += p * LO16(qq.z);
                a5 += p * HI16(qq.z);
                a6 += p * LO16(qq.w);
                a7 += p * HI16(qq.w);
            }
            q[0] = q[2]; q[1] = q[3];
            q[2] = LP(k + 4);
            q[3] = LP(k + 5);
        }
        for (; k < nquad; ++k) {                 // tail 0..1 quads
            int e4 = 4 * k + r;
            float p = (e4 < cnt) ? sp[e4 * HEADS + h2] : 0.0f;
            uint4 qq = q[0];
            a0 += p * LO16(qq.x);
            a1 += p * HI16(qq.x);
            a2 += p * LO16(qq.y);
            a3 += p * HI16(qq.y);
            a4 += p * LO16(qq.z);
            a5 += p * HI16(qq.z);
            a6 += p * LO16(qq.w);
            a7 += p * HI16(qq.w);
            q[0] = q[1]; q[1] = q[2]; q[2] = q[3];
        }
#undef LP
#undef LO16
#undef HI16

        a0 += __shfl_xor(a0, 16); a0 += __shfl_xor(a0, 32);
        a1 += __shfl_xor(a1, 16); a1 += __shfl_xor(a1, 32);
        a2 += __shfl_xor(a2, 16); a2 += __shfl_xor(a2, 32);
        a3 += __shfl_xor(a3, 16); a3 += __shfl_xor(a3, 32);
        a4 += __shfl_xor(a4, 16); a4 += __shfl_xor(a4, 32);
        a5 += __shfl_xor(a5, 16); a5 += __shfl_xor(a5, 32);
        a6 += __shfl_xor(a6, 16); a6 += __shfl_xor(a6, 32);
        a7 += __shfl_xor(a7, 16); a7 += __shfl_xor(a7, 32);

        float denom = __shfl(myl, h2 * 8);
        float inv = 1.0f / fmaxf(denom, 1e-10f);

        if (lane < 16) {
            f32x4 o0 = { a0 * inv, a1 * inv, a2 * inv, a3 * inv };
            f32x4 o1 = { a4 * inv, a5 * inv, a6 * inv, a7 * inv };
            f32x4* op = (f32x4*)(out + (size_t)n * CHANNELS) + l16 * 2;
            __builtin_nontemporal_store(o0, op);
            __builtin_nontemporal_store(o1, op + 1);
        }
    }
}

// ---------------------------------------------------------------------------
extern "C" void kernel_launch(void* const* d_in, const int* in_sizes, int n_in,
                              void* d_out, int out_size, void* d_ws, size_t ws_size,
                              hipStream_t stream) {
    const float* x   = (const float*)d_in[0];
    const int*   ei  = (const int*)  d_in[1];   // (2, N_EDGES) row-major
    const float* att = (const float*)d_in[2];
    const int* src = ei;
    const int* dst = ei + N_EDGES;
    float* out = (float*)d_out;

    // Workspace layout (no memsets: ebuf garbage guarded by cc counts, rows
    // LDS garbage guarded by cnt; cc/ls8/ld8/xb fully written each iter):
    unsigned*       ebuf = (unsigned*)d_ws;                       // NBINS*NCHUNK*CAPC (19.3 MB)
    int*            cc   = (int*)(ebuf + (size_t)NBINS * NCHUNK * CAPC);   // NBINS*NCHUNK
    float*          ls8  = (float*)(cc + (size_t)NBINS * NCHUNK);          // N_NODES*HEADS
    float*          ld8  = ls8 + (size_t)N_NODES * HEADS;                  // N_NODES*HEADS
    unsigned short* xb   = (unsigned short*)(ld8 + (size_t)N_NODES * HEADS);

    prep_kernel<<<NCHUNK + LOGIT_VB, 256, 0, stream>>>(
        x, att, src, dst, ls8, ld8, xb, ebuf, cc);
    aggregate_kernel<<<NBINS, 256, 0, stream>>>(ebuf, cc, xb, ls8, ld8, out);
}

// Round 7
// 144.936 us; speedup vs baseline: 1.0418x; 1.0418x over previous
//
#include <hip/hip_runtime.h>

#define N_NODES  50000
#define N_EDGES  600000
#define CHANNELS 128
#define HEADS    8
#define HEAD_DIM 16     // CHANNELS / HEADS
#define CAP      64     // per-node capacity; degrees ~ Poisson(12), max ~28

#define NBINS    1024   // dst bins; bin = dst*NBINS/N_NODES (~49 nodes/bin)
#define CHUNK_E  4096   // edges per chunk
#define NCHUNK   ((N_EDGES + CHUNK_E - 1) / CHUNK_E)     // 147
#define CAPC     24     // per-(chunk,bin) slice; Poisson(4), P(any overflow)~2e-7
#define NPB      52     // max nodes per bin (49) padded
#define GR       8      // bin-groups per chunk in prep (1176 scatter blocks)
#define BPG      (NBINS / GR)                            // 128 bins per group

#define LOGIT_VB ((N_NODES * (CHANNELS / 8)) / 256)      // 3125 (8 channels/thread)
#define NW       4      // waves per aggregate block

typedef float  f32x4 __attribute__((ext_vector_type(4)));   // nontemporal-store-able

// bf16 round-to-nearest-even of an fp32 bit pattern
__device__ __forceinline__ unsigned bf16rne(float f) {
    unsigned u = __float_as_uint(f);
    return (u + 0x7FFFu + ((u >> 16) & 1u)) >> 16;
}

// ---------------------------------------------------------------------------
// K1: logit sweep ∥ fixed-slice binscatter (disjoint block ranges).
//  - blocks [0, GR*NCHUNK): (grange g, chunk c).  Reads the WHOLE chunk's
//    src/dst coalesced (8x re-read, L2/L3-served) but scatters only edges
//    whose bin falls in [g*BPG, (g+1)*BPG) — 1176 blocks instead of 147
//    (R5 lesson: 147 blocks = 0.57/CU serialized the scattered line writes).
//    Rank via LDS atomic into the (chunk,bin) cell's FIXED slice
//    ebuf[bin][chunk][CAPC].  No hist/scan/global-atomic allocation
//    (R3 lesson: same-address global atomic chains serialize on home L2;
//    R1 lesson: never scatter sub-line stores across a large region —
//    here stores cluster ~4 per 96B cell).
//  - blocks [GR*NCHUNK, +LOGIT_VB): per-node logit halves + bf16(x)
//    (8 channels/thread: 32B in, 16B packed-bf16 out).
// ---------------------------------------------------------------------------
__global__ void prep_kernel(const float* __restrict__ x,
                            const float* __restrict__ att,
                            const int*   __restrict__ src,
                            const int*   __restrict__ dst,
                            float*          __restrict__ ls8,
                            float*          __restrict__ ld8,
                            unsigned short* __restrict__ xb,
                            unsigned*       __restrict__ ebuf,
                            int*            __restrict__ cc) {
    int b = blockIdx.x;
    int t = threadIdx.x;
    if (b < GR * NCHUNK) {
        int g = b / NCHUNK;                      // bin-group (magic-mul)
        int c = b - g * NCHUNK;                  // chunk
        int bin0 = g * BPG;
        __shared__ int lh[BPG];                  // rank counters, 512B
        if (t < BPG) lh[t] = 0;
        __syncthreads();
        int base = c * CHUNK_E;
#pragma unroll 4
        for (int k = 0; k < CHUNK_E / 256; ++k) {
            int e = base + t + k * 256;
            if (e < N_EDGES) {
                int d = dst[e];                  // coalesced (8x redundant)
                int s = src[e];
                unsigned bin = ((unsigned)d * NBINS) / N_NODES;
                if ((int)bin - bin0 >= 0 && (int)bin - bin0 < BPG) {
                    int r = atomicAdd(&lh[bin - bin0], 1);       // LDS atomic
                    if (r < CAPC)
                        ebuf[((size_t)bin * NCHUNK + c) * CAPC + r] =
                            (unsigned)s | ((unsigned)d << 16);
                }
            }
        }
        __syncthreads();
        if (t < BPG)
            cc[(size_t)(bin0 + t) * NCHUNK + c] = min(lh[t], CAPC);  // bin-major
        return;
    }
    int gid = (b - GR * NCHUNK) * 256 + t;       // (node, 8-channel slot)
    int n  = gid >> 4;                           // 16 slots per node
    int c8 = gid & 15;
    int h  = c8 >> 1;                            // 2 slots per head
    int j8 = c8 & 1;

    const float4* xp = (const float4*)x + (size_t)gid * 2;
    float4 v0 = xp[0], v1 = xp[1];

    // packed bf16 store: 8 channels -> uint4 (16B)
    uint4 pk;
    pk.x = bf16rne(v0.x) | (bf16rne(v0.y) << 16);
    pk.y = bf16rne(v0.z) | (bf16rne(v0.w) << 16);
    pk.z = bf16rne(v1.x) | (bf16rne(v1.y) << 16);
    pk.w = bf16rne(v1.z) | (bf16rne(v1.w) << 16);
    ((uint4*)xb)[gid] = pk;

    // att row = 32 floats = 8 float4s: [a_src(4), a_dst(4)]
    const float4* att4 = (const float4*)att;
    float4 as0 = att4[h * 8 + j8 * 2],     as1 = att4[h * 8 + j8 * 2 + 1];
    float4 ad0 = att4[h * 8 + 4 + j8 * 2], ad1 = att4[h * 8 + 5 + j8 * 2];
    float ts = v0.x*as0.x + v0.y*as0.y + v0.z*as0.z + v0.w*as0.w
             + v1.x*as1.x + v1.y*as1.y + v1.z*as1.z + v1.w*as1.w;
    float td = v0.x*ad0.x + v0.y*ad0.y + v0.z*ad0.z + v0.w*ad0.w
             + v1.x*ad1.x + v1.y*ad1.y + v1.z*ad1.z + v1.w*ad1.w;
    ts += __shfl_xor(ts, 1, 2);
    td += __shfl_xor(td, 1, 2);
    if (j8 == 0) {
        ls8[n * HEADS + h] = ts;
        ld8[n * HEADS + h] = td;
    }
}

// ---------------------------------------------------------------------------
// K2: bucket + fused GAT merged.  One block per bin (~49 nodes) — R4 geometry
// (R5's 2048 sparser bins regressed: more slice-scan waste, no occupancy gain).
// R6: pass-2 window deepened to 8 uint4 slots = 32 edges in flight (R4/R5
// counters: 2 TB/s, 25% HBM, 36% VALU -> latency-bound gather).
// Phase 1: sparse read of the bin's fixed-slice segment (slot < cc[c]),
//   LDS-atomic rank into per-node LDS rows.
// Phase 2: per-wave node loop, proven fused body:
//   Pass 1 (h=lane>>3, j=lane&7): logits in registers, 8-lane shuffle max
//     (clamped at 0 == reference's max(seg_max,0)), one exp per (edge,head)
//     -> LDS s_p, denominator reduced in-register.
//   Pass 2: 4 edges per wave-load — uint4/lane (16B), 16 lanes = one 256B
//     bf16 row; 8-slot statically-indexed uint4 window (32 edges ahead).
//     q[] must only be indexed by compile-time constants (R12: dynamic
//     indexing spills, 3.6x regression).
// rows[] slots >= cnt are uninitialized LDS: every access is `< cnt`-guarded
// or shfl-index-clamped, so garbage is never dereferenced.
// ---------------------------------------------------------------------------
__global__ void aggregate_kernel(const unsigned* __restrict__ ebuf,
                                 const int*      __restrict__ cc,
                                 const unsigned short* __restrict__ xb,
                                 const float* __restrict__ ls8,
                                 const float* __restrict__ ld8,
                                 float*       __restrict__ out) {
    __shared__ unsigned short rows[NPB * CAP];   // 6.5 KB
    __shared__ int   lcnt[NPB];
    __shared__ int   lcc[NCHUNK];                // 588 B
    __shared__ float s_p[NW * CAP * HEADS];      // 8 KB: per-wave softmax stage

    int b = blockIdx.x;
    int t = threadIdx.x;
    int n0 = (b * N_NODES + NBINS - 1) / NBINS;
    int n1 = ((b + 1) * N_NODES + NBINS - 1) / NBINS;
    int nn = n1 - n0;
    if (t < NPB) lcnt[t] = 0;
    if (t < NCHUNK) lcc[t] = cc[(size_t)b * NCHUNK + t];
    __syncthreads();

    // ---- phase 1: rank bin's edges into per-node LDS rows ----
    const unsigned* seg = ebuf + (size_t)b * NCHUNK * CAPC;
    for (int p = t; p < NCHUNK * CAPC; p += 256) {
        int c    = p / CAPC;                     // magic-mul, no HW div
        int slot = p - c * CAPC;
        if (slot < lcc[c]) {
            unsigned rec = seg[p];
            int s = (int)(rec & 0xFFFFu);
            int d = (int)(rec >> 16);
            int pos = atomicAdd(&lcnt[d - n0], 1);           // LDS atomic
            if (pos < CAP) rows[(d - n0) * CAP + pos] = (unsigned short)s;
        }
    }
    __syncthreads();

    // ---- phase 2: per-wave node loop, fused body ----
    int wave = t >> 6;
    int lane = t & 63;
    int h = lane >> 3;                           // pass-1 head
    int j = lane & 7;
    int r   = lane >> 4;                         // pass-2: which edge of quad (0..3)
    int l16 = lane & 15;                         // pass-2: channel octet
    int h2  = l16 >> 1;                          // pass-2 head
    float* sp = s_p + wave * (CAP * HEADS);

    for (int idx = wave; idx < nn; idx += NW) {
        int n = n0 + idx;
        int cnt_raw = lcnt[idx];
        int cnt = (cnt_raw > CAP) ? CAP : cnt_raw;
        int myidx = (int)rows[idx * CAP + lane];
        float ldst = ld8[n * HEADS + h];

        // ---- pass 1: logits in regs, per-head max, one exp per value ----
        float av[8];
        float mymax = -1e30f;
#pragma unroll
        for (int k = 0; k < 8; ++k) {
            int i = j + 8 * k;
            av[k] = -1e30f;
            if (i < cnt) {
                int   s  = __shfl(myidx, i);
                float lg = ls8[s * HEADS + h] + ldst;
                float a  = (lg >= 0.0f) ? lg : 0.2f * lg;   // LeakyReLU(0.2)
                av[k] = a;
                mymax = fmaxf(mymax, a);
            }
        }
#pragma unroll
        for (int o = 4; o >= 1; o >>= 1) mymax = fmaxf(mymax, __shfl_xor(mymax, o, 8));
        float m = fmaxf(mymax, 0.0f);            // reference clamps seg_max at 0

        float myl = 0.0f;
#pragma unroll
        for (int k = 0; k < 8; ++k) {
            int i = j + 8 * k;
            if (i < cnt) {
                float p = __expf(av[k] - m);
                sp[i * HEADS + h] = p;           // 2-way bank aliasing only
                myl += p;
            }
        }
#pragma unroll
        for (int o = 4; o >= 1; o >>= 1) myl += __shfl_xor(myl, o, 8);

        // ---- pass 2: weighted accumulate, 4 edges/load, 8 uint4 window ----
#define LO16(u) __uint_as_float((u) << 16)
#define HI16(u) __uint_as_float((u) & 0xFFFF0000u)
#define LP(kq) ( ((const uint4*)(xb + (size_t)__shfl(myidx, ((4*(kq)+r) < cnt) ? (4*(kq)+r) : 0) * CHANNELS))[l16] )
        uint4 q[8];
#pragma unroll
        for (int k = 0; k < 8; ++k) q[k] = LP(k);

        float a0 = 0.f, a1 = 0.f, a2 = 0.f, a3 = 0.f;
        float a4 = 0.f, a5 = 0.f, a6 = 0.f, a7 = 0.f;
        int nquad = (cnt + 3) >> 2;
        int k = 0;
        for (; k + 4 <= nquad; k += 4) {
#pragma unroll
            for (int u = 0; u < 4; ++u) {
                int e4 = 4 * (k + u) + r;
                float p = (e4 < cnt) ? sp[e4 * HEADS + h2] : 0.0f;
                uint4 qq = q[u];
                a0 += p * LO16(qq.x);
                a1 += p * HI16(qq.x);
                a2 += p * LO16(qq.y);
                a3 += p * HI16(qq.y);
                a4 += p * LO16(qq.z);
                a5 += p * HI16(qq.z);
                a6 += p * LO16(qq.w);
                a7 += p * HI16(qq.w);
            }
#pragma unroll
            for (int u = 0; u < 4; ++u) q[u] = q[u + 4];
#pragma unroll
            for (int u = 0; u < 4; ++u) q[u + 4] = LP(k + 8 + u);
        }
        for (; k < nquad; ++k) {                 // tail 0..3 quads
            int e4 = 4 * k + r;
            float p = (e4 < cnt) ? sp[e4 * HEADS + h2] : 0.0f;
            uint4 qq = q[0];
            a0 += p * LO16(qq.x);
            a1 += p * HI16(qq.x);
            a2 += p * LO16(qq.y);
            a3 += p * HI16(qq.y);
            a4 += p * LO16(qq.z);
            a5 += p * HI16(qq.z);
            a6 += p * LO16(qq.w);
            a7 += p * HI16(qq.w);
#pragma unroll
            for (int u = 0; u < 7; ++u) q[u] = q[u + 1];
        }
#undef LP
#undef LO16
#undef HI16

        a0 += __shfl_xor(a0, 16); a0 += __shfl_xor(a0, 32);
        a1 += __shfl_xor(a1, 16); a1 += __shfl_xor(a1, 32);
        a2 += __shfl_xor(a2, 16); a2 += __shfl_xor(a2, 32);
        a3 += __shfl_xor(a3, 16); a3 += __shfl_xor(a3, 32);
        a4 += __shfl_xor(a4, 16); a4 += __shfl_xor(a4, 32);
        a5 += __shfl_xor(a5, 16); a5 += __shfl_xor(a5, 32);
        a6 += __shfl_xor(a6, 16); a6 += __shfl_xor(a6, 32);
        a7 += __shfl_xor(a7, 16); a7 += __shfl_xor(a7, 32);

        float denom = __shfl(myl, h2 * 8);
        float inv = 1.0f / fmaxf(denom, 1e-10f);

        if (lane < 16) {
            f32x4 o0 = { a0 * inv, a1 * inv, a2 * inv, a3 * inv };
            f32x4 o1 = { a4 * inv, a5 * inv, a6 * inv, a7 * inv };
            f32x4* op = (f32x4*)(out + (size_t)n * CHANNELS) + l16 * 2;
            __builtin_nontemporal_store(o0, op);
            __builtin_nontemporal_store(o1, op + 1);
        }
    }
}

// ---------------------------------------------------------------------------
extern "C" void kernel_launch(void* const* d_in, const int* in_sizes, int n_in,
                              void* d_out, int out_size, void* d_ws, size_t ws_size,
                              hipStream_t stream) {
    const float* x   = (const float*)d_in[0];
    const int*   ei  = (const int*)  d_in[1];   // (2, N_EDGES) row-major
    const float* att = (const float*)d_in[2];
    const int* src = ei;
    const int* dst = ei + N_EDGES;
    float* out = (float*)d_out;

    // Workspace layout (no memsets: ebuf garbage guarded by cc counts, rows
    // LDS garbage guarded by cnt; cc/ls8/ld8/xb fully written each iter):
    unsigned*       ebuf = (unsigned*)d_ws;                       // NBINS*NCHUNK*CAPC (14.5 MB)
    int*            cc   = (int*)(ebuf + (size_t)NBINS * NCHUNK * CAPC);   // NBINS*NCHUNK
    float*          ls8  = (float*)(cc + (size_t)NBINS * NCHUNK);          // N_NODES*HEADS
    float*          ld8  = ls8 + (size_t)N_NODES * HEADS;                  // N_NODES*HEADS
    unsigned short* xb   = (unsigned short*)(ld8 + (size_t)N_NODES * HEADS);

    prep_kernel<<<GR * NCHUNK + LOGIT_VB, 256, 0, stream>>>(
        x, att, src, dst, ls8, ld8, xb, ebuf, cc);
    aggregate_kernel<<<NBINS, 256, 0, stream>>>(ebuf, cc, xb, ls8, ld8, out);
}

// Round 8
// 139.777 us; speedup vs baseline: 1.0802x; 1.0369x over previous
//
#include <hip/hip_runtime.h>

#define N_NODES  50000
#define N_EDGES  600000
#define CHANNELS 128
#define HEADS    8
#define HEAD_DIM 16     // CHANNELS / HEADS
#define CAP      64     // per-node capacity; degrees ~ Poisson(12), max ~28

#define NBINS    1024   // dst bins; bin = dst*NBINS/N_NODES (~49 nodes/bin)
#define CHUNK_E  4096   // edges per chunk
#define NCHUNK   ((N_EDGES + CHUNK_E - 1) / CHUNK_E)     // 147
#define CAPC     24     // per-(chunk,bin) slice; Poisson(4), P(any overflow)~3e-8
#define NSPLIT   2      // node-halves per bin -> 2048 aggregate blocks (8/CU resident)
#define NPBH     26     // max nodes per half-bin (25) padded

#define LOGIT_VB ((N_NODES * (CHANNELS / 8)) / 256)      // 3125 (8 channels/thread)
#define NW       4      // waves per aggregate block

typedef float  f32x4 __attribute__((ext_vector_type(4)));   // nontemporal-store-able

// bf16 round-to-nearest-even of an fp32 bit pattern
__device__ __forceinline__ unsigned bf16rne(float f) {
    unsigned u = __float_as_uint(f);
    return (u + 0x7FFFu + ((u >> 16) & 1u)) >> 16;
}

// ---------------------------------------------------------------------------
// K1 (R4-proven form): logit sweep ∥ fixed-slice binscatter, one launch.
//  - blocks [0, NCHUNK): bin the chunk's 4096 edges.  Rank via LDS atomic
//    into the (chunk,bin) cell's FIXED slice ebuf[bin][chunk][CAPC].
//    These 147 blocks run CONCURRENTLY with the 3125 logit blocks (R7
//    lesson: they were never serialized; the R6 GR-split's 8x edge re-read
//    was a net loss).  No hist/scan/global-atomic allocation (R3 lesson:
//    same-address global atomic chains serialize on the home L2; R1
//    lesson: never scatter sub-line stores across a large region — here
//    stores cluster ~4 per 96B cell).
//  - blocks [NCHUNK, NCHUNK+LOGIT_VB): per-node logit halves + bf16(x)
//    (8 channels/thread: 32B in, 16B packed-bf16 out).
// ---------------------------------------------------------------------------
__global__ void prep_kernel(const float* __restrict__ x,
                            const float* __restrict__ att,
                            const int*   __restrict__ src,
                            const int*   __restrict__ dst,
                            float*          __restrict__ ls8,
                            float*          __restrict__ ld8,
                            unsigned short* __restrict__ xb,
                            unsigned*       __restrict__ ebuf,
                            int*            __restrict__ cc) {
    int b = blockIdx.x;
    int t = threadIdx.x;
    if (b < NCHUNK) {
        __shared__ int lh[NBINS];                // rank counters, 4 KB
#pragma unroll
        for (int k = 0; k < NBINS / 256; ++k) lh[t + k * 256] = 0;
        __syncthreads();
        int base = b * CHUNK_E;
#pragma unroll 4
        for (int k = 0; k < CHUNK_E / 256; ++k) {
            int e = base + t + k * 256;
            if (e < N_EDGES) {
                int d = dst[e];
                int s = src[e];
                unsigned bin = ((unsigned)d * NBINS) / N_NODES;
                int r = atomicAdd(&lh[bin], 1);              // LDS atomic
                if (r < CAPC)
                    ebuf[((size_t)bin * NCHUNK + b) * CAPC + r] =
                        (unsigned)s | ((unsigned)d << 16);
            }
        }
        __syncthreads();
#pragma unroll
        for (int k = 0; k < NBINS / 256; ++k) {
            int bin = t + k * 256;
            cc[(size_t)bin * NCHUNK + b] = min(lh[bin], CAPC);   // bin-major for K2
        }
        return;
    }
    int gid = (b - NCHUNK) * 256 + t;            // (node, 8-channel slot)
    int n  = gid >> 4;                           // 16 slots per node
    int c8 = gid & 15;
    int h  = c8 >> 1;                            // 2 slots per head
    int j8 = c8 & 1;

    const float4* xp = (const float4*)x + (size_t)gid * 2;
    float4 v0 = xp[0], v1 = xp[1];

    // packed bf16 store: 8 channels -> uint4 (16B)
    uint4 pk;
    pk.x = bf16rne(v0.x) | (bf16rne(v0.y) << 16);
    pk.y = bf16rne(v0.z) | (bf16rne(v0.w) << 16);
    pk.z = bf16rne(v1.x) | (bf16rne(v1.y) << 16);
    pk.w = bf16rne(v1.z) | (bf16rne(v1.w) << 16);
    ((uint4*)xb)[gid] = pk;

    // att row = 32 floats = 8 float4s: [a_src(4), a_dst(4)]
    const float4* att4 = (const float4*)att;
    float4 as0 = att4[h * 8 + j8 * 2],     as1 = att4[h * 8 + j8 * 2 + 1];
    float4 ad0 = att4[h * 8 + 4 + j8 * 2], ad1 = att4[h * 8 + 5 + j8 * 2];
    float ts = v0.x*as0.x + v0.y*as0.y + v0.z*as0.z + v0.w*as0.w
             + v1.x*as1.x + v1.y*as1.y + v1.z*as1.z + v1.w*as1.w;
    float td = v0.x*ad0.x + v0.y*ad0.y + v0.z*ad0.z + v0.w*ad0.w
             + v1.x*ad1.x + v1.y*ad1.y + v1.z*ad1.z + v1.w*ad1.w;
    ts += __shfl_xor(ts, 1, 2);
    td += __shfl_xor(td, 1, 2);
    if (j8 == 0) {
        ls8[n * HEADS + h] = ts;
        ld8[n * HEADS + h] = td;
    }
}

// ---------------------------------------------------------------------------
// K2: bucket + fused GAT merged.  R8 geometry: one block per (bin, half) —
// 2048 blocks, ~25 nodes each, ~13KB LDS -> 8 blocks/CU resident (R4-R7:
// Occupancy stuck at 33-35% with 1024-block grid).
// R8 phase 1: COMPACT read — prefix-scan the bin's 147 per-chunk counts in
// LDS, then binary-search each global record index so only OCCUPIED ebuf
// slots are read (2.4MB vs 14.5MB full-slice scan at 16.6% density; R4-R7
// counters pinned beyond-L2 traffic at a ~2.1 TB/s wall, so bytes ARE time).
// Phase 2: per-wave node loop, R11/R2-proven fused body (4-slot uint4
// window; R7: 8-slot window was neutral-to-worse, reverted):
//   Pass 1 (h=lane>>3, j=lane&7): logits in registers, 8-lane shuffle max
//     (clamped at 0 == reference's max(seg_max,0)), one exp per (edge,head)
//     -> LDS s_p, denominator reduced in-register.
//   Pass 2: 4 edges per wave-load — uint4/lane (16B), 16 lanes = one 256B
//     bf16 row.  q[] must only be indexed by compile-time constants (R12:
//     dynamic indexing spills, 3.6x regression).
// rows[] slots >= cnt are uninitialized LDS: every access is `< cnt`-guarded
// or shfl-index-clamped, so garbage is never dereferenced (cnt==0 nodes
// read a garbage-but-in-workspace row and multiply it by p=0).
// ---------------------------------------------------------------------------
__global__ void aggregate_kernel(const unsigned* __restrict__ ebuf,
                                 const int*      __restrict__ cc,
                                 const unsigned short* __restrict__ xb,
                                 const float* __restrict__ ls8,
                                 const float* __restrict__ ld8,
                                 float*       __restrict__ out) {
    __shared__ unsigned short rows[NPBH * CAP];  // 3.25 KB
    __shared__ int   lcnt[NPBH];
    __shared__ int   sc[256];                    // scan workspace
    __shared__ int   P[NCHUNK + 1];              // exclusive prefix of counts
    __shared__ float s_p[NW * CAP * HEADS];      // 8 KB: per-wave softmax stage

    int blk  = blockIdx.x;
    int b    = blk >> 1;                         // bin
    int half = blk & 1;                          // node half
    int t = threadIdx.x;
    int n0 = (b * N_NODES + NBINS - 1) / NBINS;
    int n1 = ((b + 1) * N_NODES + NBINS - 1) / NBINS;
    int nn = n1 - n0;
    int hn = (nn + 1) >> 1;
    int m0 = n0 + half * hn;
    int m1 = half ? n1 : (n0 + hn);
    int nnh = m1 - m0;

    if (t < NPBH) lcnt[t] = 0;
    int v = (t < NCHUNK) ? cc[(size_t)b * NCHUNK + t] : 0;
    sc[t] = v;
    __syncthreads();
    for (int off = 1; off < 256; off <<= 1) {    // Hillis-Steele inclusive scan
        int u = (t >= off) ? sc[t - off] : 0;
        __syncthreads();
        sc[t] += u;
        __syncthreads();
    }
    if (t < NCHUNK) P[t + 1] = sc[t];
    if (t == 0) P[0] = 0;
    __syncthreads();
    int R = P[NCHUNK];                           // total records in this bin (~586)

    // ---- phase 1: compact read of occupied slots only, rank into rows ----
    const unsigned* seg = ebuf + (size_t)b * NCHUNK * CAPC;
    for (int g = t; g < R; g += 256) {
        int lo = 0, hi = NCHUNK;                 // find c: P[c] <= g < P[c+1]
        while (hi - lo > 1) {
            int mc = (lo + hi) >> 1;
            if (P[mc] <= g) lo = mc; else hi = mc;
        }
        int slot = g - P[lo];
        unsigned rec = seg[lo * CAPC + slot];
        int s = (int)(rec & 0xFFFFu);
        int d = (int)(rec >> 16);
        if (d >= m0 && d < m1) {                 // this half's nodes only
            int pos = atomicAdd(&lcnt[d - m0], 1);           // LDS atomic
            if (pos < CAP) rows[(d - m0) * CAP + pos] = (unsigned short)s;
        }
    }
    __syncthreads();

    // ---- phase 2: per-wave node loop, fused body ----
    int wave = t >> 6;
    int lane = t & 63;
    int h = lane >> 3;                           // pass-1 head
    int j = lane & 7;
    int r   = lane >> 4;                         // pass-2: which edge of quad (0..3)
    int l16 = lane & 15;                         // pass-2: channel octet
    int h2  = l16 >> 1;                          // pass-2 head
    float* sp = s_p + wave * (CAP * HEADS);

    for (int idx = wave; idx < nnh; idx += NW) {
        int n = m0 + idx;
        int cnt_raw = lcnt[idx];
        int cnt = (cnt_raw > CAP) ? CAP : cnt_raw;
        int myidx = (int)rows[idx * CAP + lane];
        float ldst = ld8[n * HEADS + h];

        // ---- pass 1: logits in regs, per-head max, one exp per value ----
        float av[8];
        float mymax = -1e30f;
#pragma unroll
        for (int k = 0; k < 8; ++k) {
            int i = j + 8 * k;
            av[k] = -1e30f;
            if (i < cnt) {
                int   s  = __shfl(myidx, i);
                float lg = ls8[s * HEADS + h] + ldst;
                float a  = (lg >= 0.0f) ? lg : 0.2f * lg;   // LeakyReLU(0.2)
                av[k] = a;
                mymax = fmaxf(mymax, a);
            }
        }
#pragma unroll
        for (int o = 4; o >= 1; o >>= 1) mymax = fmaxf(mymax, __shfl_xor(mymax, o, 8));
        float m = fmaxf(mymax, 0.0f);            // reference clamps seg_max at 0

        float myl = 0.0f;
#pragma unroll
        for (int k = 0; k < 8; ++k) {
            int i = j + 8 * k;
            if (i < cnt) {
                float p = __expf(av[k] - m);
                sp[i * HEADS + h] = p;           // 2-way bank aliasing only
                myl += p;
            }
        }
#pragma unroll
        for (int o = 4; o >= 1; o >>= 1) myl += __shfl_xor(myl, o, 8);

        // ---- pass 2: weighted accumulate, 4 edges/load, 4 uint4 window ----
#define LO16(u) __uint_as_float((u) << 16)
#define HI16(u) __uint_as_float((u) & 0xFFFF0000u)
#define LP(kq) ( ((const uint4*)(xb + (size_t)__shfl(myidx, ((4*(kq)+r) < cnt) ? (4*(kq)+r) : 0) * CHANNELS))[l16] )
        uint4 q[4];
#pragma unroll
        for (int k = 0; k < 4; ++k) q[k] = LP(k);

        float a0 = 0.f, a1 = 0.f, a2 = 0.f, a3 = 0.f;
        float a4 = 0.f, a5 = 0.f, a6 = 0.f, a7 = 0.f;
        int nquad = (cnt + 3) >> 2;
        int k = 0;
        for (; k + 2 <= nquad; k += 2) {
#pragma unroll
            for (int u = 0; u < 2; ++u) {
                int e4 = 4 * (k + u) + r;
                float p = (e4 < cnt) ? sp[e4 * HEADS + h2] : 0.0f;
                uint4 qq = q[u];
                a0 += p * LO16(qq.x);
                a1 += p * HI16(qq.x);
                a2 += p * LO16(qq.y);
                a3 += p * HI16(qq.y);
                a4 += p * LO16(qq.z);
                a5 += p * HI16(qq.z);
                a6 += p * LO16(qq.w);
                a7 += p * HI16(qq.w);
            }
            q[0] = q[2]; q[1] = q[3];
            q[2] = LP(k + 4);
            q[3] = LP(k + 5);
        }
        for (; k < nquad; ++k) {                 // tail 0..1 quads
            int e4 = 4 * k + r;
            float p = (e4 < cnt) ? sp[e4 * HEADS + h2] : 0.0f;
            uint4 qq = q[0];
            a0 += p * LO16(qq.x);
            a1 += p * HI16(qq.x);
            a2 += p * LO16(qq.y);
            a3 += p * HI16(qq.y);
            a4 += p * LO16(qq.z);
            a5 += p * HI16(qq.z);
            a6 += p * LO16(qq.w);
            a7 += p * HI16(qq.w);
            q[0] = q[1]; q[1] = q[2]; q[2] = q[3];
        }
#undef LP
#undef LO16
#undef HI16

        a0 += __shfl_xor(a0, 16); a0 += __shfl_xor(a0, 32);
        a1 += __shfl_xor(a1, 16); a1 += __shfl_xor(a1, 32);
        a2 += __shfl_xor(a2, 16); a2 += __shfl_xor(a2, 32);
        a3 += __shfl_xor(a3, 16); a3 += __shfl_xor(a3, 32);
        a4 += __shfl_xor(a4, 16); a4 += __shfl_xor(a4, 32);
        a5 += __shfl_xor(a5, 16); a5 += __shfl_xor(a5, 32);
        a6 += __shfl_xor(a6, 16); a6 += __shfl_xor(a6, 32);
        a7 += __shfl_xor(a7, 16); a7 += __shfl_xor(a7, 32);

        float denom = __shfl(myl, h2 * 8);
        float inv = 1.0f / fmaxf(denom, 1e-10f);

        if (lane < 16) {
            f32x4 o0 = { a0 * inv, a1 * inv, a2 * inv, a3 * inv };
            f32x4 o1 = { a4 * inv, a5 * inv, a6 * inv, a7 * inv };
            f32x4* op = (f32x4*)(out + (size_t)n * CHANNELS) + l16 * 2;
            __builtin_nontemporal_store(o0, op);
            __builtin_nontemporal_store(o1, op + 1);
        }
    }
}

// ---------------------------------------------------------------------------
extern "C" void kernel_launch(void* const* d_in, const int* in_sizes, int n_in,
                              void* d_out, int out_size, void* d_ws, size_t ws_size,
                              hipStream_t stream) {
    const float* x   = (const float*)d_in[0];
    const int*   ei  = (const int*)  d_in[1];   // (2, N_EDGES) row-major
    const float* att = (const float*)d_in[2];
    const int* src = ei;
    const int* dst = ei + N_EDGES;
    float* out = (float*)d_out;

    // Workspace layout (no memsets: ebuf garbage guarded by cc counts, rows
    // LDS garbage guarded by cnt; cc/ls8/ld8/xb fully written each iter):
    unsigned*       ebuf = (unsigned*)d_ws;                       // NBINS*NCHUNK*CAPC (14.5 MB)
    int*            cc   = (int*)(ebuf + (size_t)NBINS * NCHUNK * CAPC);   // NBINS*NCHUNK
    float*          ls8  = (float*)(cc + (size_t)NBINS * NCHUNK);          // N_NODES*HEADS
    float*          ld8  = ls8 + (size_t)N_NODES * HEADS;                  // N_NODES*HEADS
    unsigned short* xb   = (unsigned short*)(ld8 + (size_t)N_NODES * HEADS);

    prep_kernel<<<NCHUNK + LOGIT_VB, 256, 0, stream>>>(
        x, att, src, dst, ls8, ld8, xb, ebuf, cc);
    aggregate_kernel<<<NBINS * NSPLIT, 256, 0, stream>>>(ebuf, cc, xb, ls8, ld8, out);
}

// Round 9
// 137.599 us; speedup vs baseline: 1.0973x; 1.0158x over previous
//
#include <hip/hip_runtime.h>

#define N_NODES  50000
#define N_EDGES  600000
#define CHANNELS 128
#define HEADS    8
#define HEAD_DIM 16     // CHANNELS / HEADS
#define CAP      64     // per-node capacity; degrees ~ Poisson(12), max ~28

#define NBINS    1024   // dst bins; bin = dst*NBINS/N_NODES (~49 nodes/bin)
#define CHUNK_E  2048   // edges per chunk (R9: halved -> 2x scatter blocks)
#define NCHUNK   ((N_EDGES + CHUNK_E - 1) / CHUNK_E)     // 293
#define CAPC     16     // per-(chunk,bin) slice = one 64B line; Poisson(2), P(any overflow)~2e-5
#define NPB      52     // max nodes per bin (49) padded

#define LOGIT_VB ((N_NODES * (CHANNELS / 8)) / 256)      // 3125 (8 channels/thread)
#define NW       4      // waves per aggregate block

typedef float  f32x4 __attribute__((ext_vector_type(4)));   // nontemporal-store-able

// bf16 round-to-nearest-even of an fp32 bit pattern
__device__ __forceinline__ unsigned bf16rne(float f) {
    unsigned u = __float_as_uint(f);
    return (u + 0x7FFFu + ((u >> 16) & 1u)) >> 16;
}

// ---------------------------------------------------------------------------
// K1: logit sweep ∥ fixed-slice binscatter (disjoint block ranges, one
// launch so both halves co-schedule).
//  - blocks [0, NCHUNK): bin the chunk's 2048 edges.  Rank via LDS atomic
//    into the (chunk,bin) cell's FIXED 64B slice ebuf[bin][chunk][CAPC].
//    R9: 293 blocks (was 147) — the scatter is uncoalesced-store-
//    latency-bound, so block count ~ throughput (R0: 586-block variant ran
//    ~7us; R4's 147-block ~4x-serial chain is the suspected ~30us pig).
//    No hist/scan/global-atomic allocation (R3 lesson: same-address global
//    atomic chains serialize on the home L2; R1 lesson: never scatter
//    sub-line stores across a large region — here stores cluster ~2 per
//    64B cell).
//  - blocks [NCHUNK, NCHUNK+LOGIT_VB): per-node logit halves + bf16(x)
//    (8 channels/thread: 32B in, 16B packed-bf16 out).
// ---------------------------------------------------------------------------
__global__ void prep_kernel(const float* __restrict__ x,
                            const float* __restrict__ att,
                            const int*   __restrict__ src,
                            const int*   __restrict__ dst,
                            float*          __restrict__ ls8,
                            float*          __restrict__ ld8,
                            unsigned short* __restrict__ xb,
                            unsigned*       __restrict__ ebuf,
                            int*            __restrict__ cc) {
    int b = blockIdx.x;
    int t = threadIdx.x;
    if (b < NCHUNK) {
        __shared__ int lh[NBINS];                // rank counters, 4 KB
#pragma unroll
        for (int k = 0; k < NBINS / 256; ++k) lh[t + k * 256] = 0;
        __syncthreads();
        int base = b * CHUNK_E;
#pragma unroll 4
        for (int k = 0; k < CHUNK_E / 256; ++k) {
            int e = base + t + k * 256;
            if (e < N_EDGES) {
                int d = dst[e];
                int s = src[e];
                unsigned bin = ((unsigned)d * NBINS) / N_NODES;
                int r = atomicAdd(&lh[bin], 1);              // LDS atomic
                if (r < CAPC)
                    ebuf[((size_t)bin * NCHUNK + b) * CAPC + r] =
                        (unsigned)s | ((unsigned)d << 16);
            }
        }
        __syncthreads();
#pragma unroll
        for (int k = 0; k < NBINS / 256; ++k) {
            int bin = t + k * 256;
            cc[(size_t)bin * NCHUNK + b] = min(lh[bin], CAPC);   // bin-major for K2
        }
        return;
    }
    int gid = (b - NCHUNK) * 256 + t;            // (node, 8-channel slot)
    int n  = gid >> 4;                           // 16 slots per node
    int c8 = gid & 15;
    int h  = c8 >> 1;                            // 2 slots per head
    int j8 = c8 & 1;

    const float4* xp = (const float4*)x + (size_t)gid * 2;
    float4 v0 = xp[0], v1 = xp[1];

    // packed bf16 store: 8 channels -> uint4 (16B)
    uint4 pk;
    pk.x = bf16rne(v0.x) | (bf16rne(v0.y) << 16);
    pk.y = bf16rne(v0.z) | (bf16rne(v0.w) << 16);
    pk.z = bf16rne(v1.x) | (bf16rne(v1.y) << 16);
    pk.w = bf16rne(v1.z) | (bf16rne(v1.w) << 16);
    ((uint4*)xb)[gid] = pk;

    // att row = 32 floats = 8 float4s: [a_src(4), a_dst(4)]
    const float4* att4 = (const float4*)att;
    float4 as0 = att4[h * 8 + j8 * 2],     as1 = att4[h * 8 + j8 * 2 + 1];
    float4 ad0 = att4[h * 8 + 4 + j8 * 2], ad1 = att4[h * 8 + 5 + j8 * 2];
    float ts = v0.x*as0.x + v0.y*as0.y + v0.z*as0.z + v0.w*as0.w
             + v1.x*as1.x + v1.y*as1.y + v1.z*as1.z + v1.w*as1.w;
    float td = v0.x*ad0.x + v0.y*ad0.y + v0.z*ad0.z + v0.w*ad0.w
             + v1.x*ad1.x + v1.y*ad1.y + v1.z*ad1.z + v1.w*ad1.w;
    ts += __shfl_xor(ts, 1, 2);
    td += __shfl_xor(td, 1, 2);
    if (j8 == 0) {
        ls8[n * HEADS + h] = ts;
        ld8[n * HEADS + h] = td;
    }
}

// ---------------------------------------------------------------------------
// K2: bucket + fused GAT merged — R4's exact proven body (best of five
// geometry variants: 51.3us; R5/R6/R8 variations all 53-56us, reverted).
// One block per bin (~49 nodes).
// Phase 1: full-slice scan of the bin's segment (slot < cc[c]), LDS-atomic
//   rank into per-node LDS rows.  (R8's compact binary-search read raised
//   FETCH, reverted.)
// Phase 2: per-wave node loop, proven fused body:
//   Pass 1 (h=lane>>3, j=lane&7): logits in registers, 8-lane shuffle max
//     (clamped at 0 == reference's max(seg_max,0)), one exp per (edge,head)
//     -> LDS s_p, denominator reduced in-register.
//   Pass 2: 4 edges per wave-load — uint4/lane (16B), 16 lanes = one 256B
//     bf16 row; 4-slot statically-indexed uint4 window (R6: 8-slot was
//     neutral-to-worse).  q[] must only be indexed by compile-time
//     constants (R12: dynamic indexing spills, 3.6x regression).
// rows[] slots >= cnt are uninitialized LDS: every access is `< cnt`-guarded
// or shfl-index-clamped, so garbage is never dereferenced.
// ---------------------------------------------------------------------------
__global__ void aggregate_kernel(const unsigned* __restrict__ ebuf,
                                 const int*      __restrict__ cc,
                                 const unsigned short* __restrict__ xb,
                                 const float* __restrict__ ls8,
                                 const float* __restrict__ ld8,
                                 float*       __restrict__ out) {
    __shared__ unsigned short rows[NPB * CAP];   // 6.5 KB
    __shared__ int   lcnt[NPB];
    __shared__ int   lcc[NCHUNK];                // 1.2 KB
    __shared__ float s_p[NW * CAP * HEADS];      // 8 KB: per-wave softmax stage

    int b = blockIdx.x;
    int t = threadIdx.x;
    int n0 = (b * N_NODES + NBINS - 1) / NBINS;
    int n1 = ((b + 1) * N_NODES + NBINS - 1) / NBINS;
    int nn = n1 - n0;
    if (t < NPB) lcnt[t] = 0;
    for (int i = t; i < NCHUNK; i += 256) lcc[i] = cc[(size_t)b * NCHUNK + i];
    __syncthreads();

    // ---- phase 1: rank bin's edges into per-node LDS rows ----
    const unsigned* seg = ebuf + (size_t)b * NCHUNK * CAPC;
    for (int p = t; p < NCHUNK * CAPC; p += 256) {
        int c    = p >> 4;                       // CAPC = 16
        int slot = p & 15;
        if (slot < lcc[c]) {
            unsigned rec = seg[p];
            int s = (int)(rec & 0xFFFFu);
            int d = (int)(rec >> 16);
            int pos = atomicAdd(&lcnt[d - n0], 1);           // LDS atomic
            if (pos < CAP) rows[(d - n0) * CAP + pos] = (unsigned short)s;
        }
    }
    __syncthreads();

    // ---- phase 2: per-wave node loop, fused body ----
    int wave = t >> 6;
    int lane = t & 63;
    int h = lane >> 3;                           // pass-1 head
    int j = lane & 7;
    int r   = lane >> 4;                         // pass-2: which edge of quad (0..3)
    int l16 = lane & 15;                         // pass-2: channel octet
    int h2  = l16 >> 1;                          // pass-2 head
    float* sp = s_p + wave * (CAP * HEADS);

    for (int idx = wave; idx < nn; idx += NW) {
        int n = n0 + idx;
        int cnt_raw = lcnt[idx];
        int cnt = (cnt_raw > CAP) ? CAP : cnt_raw;
        int myidx = (int)rows[idx * CAP + lane];
        float ldst = ld8[n * HEADS + h];

        // ---- pass 1: logits in regs, per-head max, one exp per value ----
        float av[8];
        float mymax = -1e30f;
#pragma unroll
        for (int k = 0; k < 8; ++k) {
            int i = j + 8 * k;
            av[k] = -1e30f;
            if (i < cnt) {
                int   s  = __shfl(myidx, i);
                float lg = ls8[s * HEADS + h] + ldst;
                float a  = (lg >= 0.0f) ? lg : 0.2f * lg;   // LeakyReLU(0.2)
                av[k] = a;
                mymax = fmaxf(mymax, a);
            }
        }
#pragma unroll
        for (int o = 4; o >= 1; o >>= 1) mymax = fmaxf(mymax, __shfl_xor(mymax, o, 8));
        float m = fmaxf(mymax, 0.0f);            // reference clamps seg_max at 0

        float myl = 0.0f;
#pragma unroll
        for (int k = 0; k < 8; ++k) {
            int i = j + 8 * k;
            if (i < cnt) {
                float p = __expf(av[k] - m);
                sp[i * HEADS + h] = p;           // 2-way bank aliasing only
                myl += p;
            }
        }
#pragma unroll
        for (int o = 4; o >= 1; o >>= 1) myl += __shfl_xor(myl, o, 8);

        // ---- pass 2: weighted accumulate, 4 edges/load, 4 uint4 window ----
#define LO16(u) __uint_as_float((u) << 16)
#define HI16(u) __uint_as_float((u) & 0xFFFF0000u)
#define LP(kq) ( ((const uint4*)(xb + (size_t)__shfl(myidx, ((4*(kq)+r) < cnt) ? (4*(kq)+r) : 0) * CHANNELS))[l16] )
        uint4 q[4];
#pragma unroll
        for (int k = 0; k < 4; ++k) q[k] = LP(k);

        float a0 = 0.f, a1 = 0.f, a2 = 0.f, a3 = 0.f;
        float a4 = 0.f, a5 = 0.f, a6 = 0.f, a7 = 0.f;
        int nquad = (cnt + 3) >> 2;
        int k = 0;
        for (; k + 2 <= nquad; k += 2) {
#pragma unroll
            for (int u = 0; u < 2; ++u) {
                int e4 = 4 * (k + u) + r;
                float p = (e4 < cnt) ? sp[e4 * HEADS + h2] : 0.0f;
                uint4 qq = q[u];
                a0 += p * LO16(qq.x);
                a1 += p * HI16(qq.x);
                a2 += p * LO16(qq.y);
                a3 += p * HI16(qq.y);
                a4 += p * LO16(qq.z);
                a5 += p * HI16(qq.z);
                a6 += p * LO16(qq.w);
                a7 += p * HI16(qq.w);
            }
            q[0] = q[2]; q[1] = q[3];
            q[2] = LP(k + 4);
            q[3] = LP(k + 5);
        }
        for (; k < nquad; ++k) {                 // tail 0..1 quads
            int e4 = 4 * k + r;
            float p = (e4 < cnt) ? sp[e4 * HEADS + h2] : 0.0f;
            uint4 qq = q[0];
            a0 += p * LO16(qq.x);
            a1 += p * HI16(qq.x);
            a2 += p * LO16(qq.y);
            a3 += p * HI16(qq.y);
            a4 += p * LO16(qq.z);
            a5 += p * HI16(qq.z);
            a6 += p * LO16(qq.w);
            a7 += p * HI16(qq.w);
            q[0] = q[1]; q[1] = q[2]; q[2] = q[3];
        }
#undef LP
#undef LO16
#undef HI16

        a0 += __shfl_xor(a0, 16); a0 += __shfl_xor(a0, 32);
        a1 += __shfl_xor(a1, 16); a1 += __shfl_xor(a1, 32);
        a2 += __shfl_xor(a2, 16); a2 += __shfl_xor(a2, 32);
        a3 += __shfl_xor(a3, 16); a3 += __shfl_xor(a3, 32);
        a4 += __shfl_xor(a4, 16); a4 += __shfl_xor(a4, 32);
        a5 += __shfl_xor(a5, 16); a5 += __shfl_xor(a5, 32);
        a6 += __shfl_xor(a6, 16); a6 += __shfl_xor(a6, 32);
        a7 += __shfl_xor(a7, 16); a7 += __shfl_xor(a7, 32);

        float denom = __shfl(myl, h2 * 8);
        float inv = 1.0f / fmaxf(denom, 1e-10f);

        if (lane < 16) {
            f32x4 o0 = { a0 * inv, a1 * inv, a2 * inv, a3 * inv };
            f32x4 o1 = { a4 * inv, a5 * inv, a6 * inv, a7 * inv };
            f32x4* op = (f32x4*)(out + (size_t)n * CHANNELS) + l16 * 2;
            __builtin_nontemporal_store(o0, op);
            __builtin_nontemporal_store(o1, op + 1);
        }
    }
}

// ---------------------------------------------------------------------------
extern "C" void kernel_launch(void* const* d_in, const int* in_sizes, int n_in,
                              void* d_out, int out_size, void* d_ws, size_t ws_size,
                              hipStream_t stream) {
    const float* x   = (const float*)d_in[0];
    const int*   ei  = (const int*)  d_in[1];   // (2, N_EDGES) row-major
    const float* att = (const float*)d_in[2];
    const int* src = ei;
    const int* dst = ei + N_EDGES;
    float* out = (float*)d_out;

    // Workspace layout (no memsets: ebuf garbage guarded by cc counts, rows
    // LDS garbage guarded by cnt; cc/ls8/ld8/xb fully written each iter):
    unsigned*       ebuf = (unsigned*)d_ws;                       // NBINS*NCHUNK*CAPC (19.2 MB)
    int*            cc   = (int*)(ebuf + (size_t)NBINS * NCHUNK * CAPC);   // NBINS*NCHUNK
    float*          ls8  = (float*)(cc + (size_t)NBINS * NCHUNK);          // N_NODES*HEADS
    float*          ld8  = ls8 + (size_t)N_NODES * HEADS;                  // N_NODES*HEADS
    unsigned short* xb   = (unsigned short*)(ld8 + (size_t)N_NODES * HEADS);

    prep_kernel<<<NCHUNK + LOGIT_VB, 256, 0, stream>>>(
        x, att, src, dst, ls8, ld8, xb, ebuf, cc);
    aggregate_kernel<<<NBINS, 256, 0, stream>>>(ebuf, cc, xb, ls8, ld8, out);
}